// Round 12
// baseline (158.245 us; speedup 1.0000x reference)
//
#include <hip/hip_runtime.h>
#include <hip/hip_cooperative_groups.h>
#include <hip/hip_bf16.h>
#include <stdint.h>

namespace cg = cooperative_groups;

#define NROWS 100000
#define INDIM 512
#define HID 128
#define NCLS 10
#define LEAKY_ALPHA 0.2f
#define GSTR 24
#define NTILES ((NROWS + 127) / 128)

typedef __bf16 bf16x8_t __attribute__((ext_vector_type(8)));
typedef __bf16 bf16x4_t __attribute__((ext_vector_type(4)));
typedef float f32x4_t __attribute__((ext_vector_type(4)));
typedef unsigned short ushort8_t __attribute__((ext_vector_type(8)));

union Frag {
    bf16x8_t v8;
    bf16x4_t v4[2];
    unsigned short u[8];
};

__device__ __forceinline__ unsigned short f2bf(float x) {
    union { __hip_bfloat16 b; unsigned short u; } cv;
    cv.b = __float2bfloat16(x);
    return cv.u;
}

__device__ __forceinline__ int img_addr(int r, int kk) {
    int p = r >> 1;
    int o = ((r & 1) << 6) | (kk << 1);
    return (p << 7) | ((((o >> 4) ^ (p & 7)) << 4) | (o & 15));
}

__device__ __forceinline__ void gload_lds16(const void* g, void* l) {
    __builtin_amdgcn_global_load_lds(
        (const __attribute__((address_space(1))) unsigned int*)g,
        (__attribute__((address_space(3))) unsigned int*)l, 16, 0, 0);
}

// ---------------- shared-phase device bodies (used by fused + fallback) ----------------

struct PrepSm { float Vl[HID * NCLS]; float Pl[2][HID][10]; float Cl[32][132]; };
struct MainSm { unsigned short Qs[16384]; unsigned short As[2][4096]; };
union SMem { PrepSm p; MainSm m; };   // 49152 B

__device__ __forceinline__ void prep_body(
    PrepSm& sm, int b, int tid,
    const float* __restrict__ C, const float* __restrict__ W, const float* __restrict__ V,
    unsigned short* __restrict__ Qimg) {
    for (int i = tid; i < HID * NCLS; i += 256) sm.Vl[i] = V[i];
    __syncthreads();
    {
        const int half = tid >> 7, j = tid & 127;
        const float* wr = W + (half * HID + j) * HID;
        float s[NCLS];
#pragma unroll
        for (int c = 0; c < NCLS; ++c) s[c] = 0.f;
        for (int m = 0; m < HID; m += 4) {
            float4 wv = *reinterpret_cast<const float4*>(wr + m);
            float wa[4] = {wv.x, wv.y, wv.z, wv.w};
#pragma unroll
            for (int u = 0; u < 4; ++u)
#pragma unroll
                for (int c = 0; c < NCLS; ++c) s[c] += wa[u] * sm.Vl[(m + u) * NCLS + c];
        }
#pragma unroll
        for (int c = 0; c < NCLS; ++c) sm.Pl[half][j][c] = s[c];
    }
    const int k0 = b << 5;
    {
        const int kr = tid >> 3, ns = (tid & 7) << 4;
        const float4* src = reinterpret_cast<const float4*>(C + (k0 + kr) * HID + ns);
#pragma unroll
        for (int j = 0; j < 4; ++j)
            *reinterpret_cast<float4*>(&sm.Cl[kr][ns + 4 * j]) = src[j];
    }
    __syncthreads();
    for (int e = tid; e < 32 * 32; e += 256) {
        const int n = e >> 5, kl = e & 31;
        const int half = n >> 4, c = n & 15;
        float s = 0.f;
        if (c < NCLS) {
#pragma unroll 4
            for (int j = 0; j < HID; ++j) s += sm.Cl[kl][j] * sm.Pl[half][j][c];
        }
        *(unsigned short*)((char*)Qimg + b * 2048 + img_addr(n, kl)) = f2bf(s);
    }
}

// One 128-row gemm tile, r9 structure. stage_q: also stage Q + barrier.
__device__ __forceinline__ void gemm_tile(
    MainSm& sm, int tile, bool stage_q, int tid,
    const float* __restrict__ A, const unsigned short* __restrict__ Qimg,
    float* __restrict__ G) {
    const int w    = tid >> 6;
    const int lane = tid & 63;
    const int l15  = lane & 15;
    const int kg   = (lane >> 4) << 2;
    const long row0 = (long)tile * 128;

    if (stage_q) {
#pragma unroll
        for (int j = 0; j < 8; ++j) {
            const int off = (j * 4 + w) * 1024;
            gload_lds16((const char*)Qimg + off + lane * 16, (char*)sm.Qs + off);
        }
    }

    const int ar_s = tid >> 1;
    const int kh   = (tid & 1) << 4;
    long gr = row0 + ar_s;
    if (gr >= NROWS) gr = NROWS - 1;
    const float* asrc = A + gr * INDIM + kh;
    const int aw0 = img_addr(ar_s, kh);
    const int aw1 = img_addr(ar_s, kh + 8);

    int ard0[2], ard1[2], brd0[2], brd1[2];
#pragma unroll
    for (int ii = 0; ii < 2; ++ii) {
        int r = w * 32 + ii * 16 + l15;
        ard0[ii] = img_addr(r, kg);
        ard1[ii] = img_addr(r, kg + 16);
    }
#pragma unroll
    for (int f = 0; f < 2; ++f) {
        brd0[f] = img_addr(f * 16 + l15, kg);
        brd1[f] = img_addr(f * 16 + l15, kg + 16);
    }

    f32x4_t acc[2][2];
#pragma unroll
    for (int i = 0; i < 2; ++i)
#pragma unroll
        for (int f = 0; f < 2; ++f)
#pragma unroll
            for (int r = 0; r < 4; ++r) acc[i][f][r] = 0.f;

    const char* asb = (const char*)&sm.As[0][0];
    const char* bsb = (const char*)&sm.Qs[0];

    float4 qA[4], qB[4], qC[4];

    {
        float4 v[4];
#pragma unroll
        for (int j = 0; j < 4; ++j) v[j] = *reinterpret_cast<const float4*>(asrc + 4 * j);
        ushort8_t lo, hi;
#pragma unroll
        for (int e = 0; e < 4; ++e) {
            lo[e] = f2bf(v[0][e]); lo[4 + e] = f2bf(v[1][e]);
            hi[e] = f2bf(v[2][e]); hi[4 + e] = f2bf(v[3][e]);
        }
        *(ushort8_t*)((char*)asb + aw0) = lo;
        *(ushort8_t*)((char*)asb + aw1) = hi;
    }
#pragma unroll
    for (int j = 0; j < 4; ++j) qB[j] = *reinterpret_cast<const float4*>(asrc + 32 + 4 * j);
#pragma unroll
    for (int j = 0; j < 4; ++j) qC[j] = *reinterpret_cast<const float4*>(asrc + 64 + 4 * j);
#pragma unroll
    for (int j = 0; j < 4; ++j) qA[j] = *reinterpret_cast<const float4*>(asrc + 96 + 4 * j);

    if (stage_q) __syncthreads();   // Q visible to all waves (once per block)

#pragma unroll
    for (int t = 0; t < 16; ++t) {
        const int cur = t & 1;
        Frag fa[2], fb[2];
#pragma unroll
        for (int ii = 0; ii < 2; ++ii) {
            fa[ii].v4[0] = *(const bf16x4_t*)(asb + cur * 8192 + ard0[ii]);
            fa[ii].v4[1] = *(const bf16x4_t*)(asb + cur * 8192 + ard1[ii]);
        }
#pragma unroll
        for (int f = 0; f < 2; ++f) {
            fb[f].v4[0] = *(const bf16x4_t*)(bsb + t * 2048 + brd0[f]);
            fb[f].v4[1] = *(const bf16x4_t*)(bsb + t * 2048 + brd1[f]);
        }
#pragma unroll
        for (int ii = 0; ii < 2; ++ii)
#pragma unroll
            for (int f = 0; f < 2; ++f)
                acc[ii][f] = __builtin_amdgcn_mfma_f32_16x16x32_bf16(fa[ii].v8, fb[f].v8, acc[ii][f], 0, 0, 0);

        if (t < 15) {
            const int slot = (t + 1) % 3;
            ushort8_t lo, hi;
            if (slot == 0) {
#pragma unroll
                for (int e = 0; e < 4; ++e) {
                    lo[e] = f2bf(qA[0][e]); lo[4 + e] = f2bf(qA[1][e]);
                    hi[e] = f2bf(qA[2][e]); hi[4 + e] = f2bf(qA[3][e]);
                }
            } else if (slot == 1) {
#pragma unroll
                for (int e = 0; e < 4; ++e) {
                    lo[e] = f2bf(qB[0][e]); lo[4 + e] = f2bf(qB[1][e]);
                    hi[e] = f2bf(qB[2][e]); hi[4 + e] = f2bf(qB[3][e]);
                }
            } else {
#pragma unroll
                for (int e = 0; e < 4; ++e) {
                    lo[e] = f2bf(qC[0][e]); lo[4 + e] = f2bf(qC[1][e]);
                    hi[e] = f2bf(qC[2][e]); hi[4 + e] = f2bf(qC[3][e]);
                }
            }
            *(ushort8_t*)((char*)asb + (cur ^ 1) * 8192 + aw0) = lo;
            *(ushort8_t*)((char*)asb + (cur ^ 1) * 8192 + aw1) = hi;

            if (t + 4 <= 15) {
                const float* src = asrc + (t + 4) * 32;
                if (slot == 0) {
#pragma unroll
                    for (int j = 0; j < 4; ++j) qA[j] = *reinterpret_cast<const float4*>(src + 4 * j);
                } else if (slot == 1) {
#pragma unroll
                    for (int j = 0; j < 4; ++j) qB[j] = *reinterpret_cast<const float4*>(src + 4 * j);
                } else {
#pragma unroll
                    for (int j = 0; j < 4; ++j) qC[j] = *reinterpret_cast<const float4*>(src + 4 * j);
                }
            }
        }
    }

    const int rq_ = (lane >> 4) << 2;
#pragma unroll
    for (int ii = 0; ii < 2; ++ii)
#pragma unroll
        for (int r = 0; r < 4; ++r) {
            long grow = row0 + w * 32 + ii * 16 + rq_ + r;
            if (l15 < NCLS && grow < NROWS) {
                G[grow * GSTR + l15]      = acc[ii][0][r];
                G[grow * GSTR + 12 + l15] = acc[ii][1][r];
            }
        }
}

__device__ __forceinline__ void epi_row(
    long i, const float* __restrict__ G,
    const int* __restrict__ n1, const int* __restrict__ n2,
    float* __restrict__ Out) {
    const float* g1 = G + (long)n1[i] * GSTR;
    const float* g2 = G + (long)n2[i] * GSTR + 12;

    float4 a0 = *(const float4*)(g1);
    float4 a1 = *(const float4*)(g1 + 4);
    float2 a2 = *(const float2*)(g1 + 8);
    float4 b0 = *(const float4*)(g2);
    float4 b1 = *(const float4*)(g2 + 4);
    float2 b2 = *(const float2*)(g2 + 8);

    float x[NCLS] = {a0.x + b0.x, a0.y + b0.y, a0.z + b0.z, a0.w + b0.w,
                     a1.x + b1.x, a1.y + b1.y, a1.z + b1.z, a1.w + b1.w,
                     a2.x + b2.x, a2.y + b2.y};
    float m = -1e30f;
#pragma unroll
    for (int c = 0; c < NCLS; ++c) {
        x[c] = (x[c] >= 0.f) ? x[c] : LEAKY_ALPHA * x[c];
        m = fmaxf(m, x[c]);
    }
    float sum = 0.f;
#pragma unroll
    for (int c = 0; c < NCLS; ++c) sum += __expf(x[c] - m);
    const float lse = m + __logf(sum);
    float2* o = (float2*)(Out + i * NCLS);
#pragma unroll
    for (int j = 0; j < 5; ++j) {
        float2 v = {x[2 * j] - lse, x[2 * j + 1] - lse};
        o[j] = v;
    }
}

// ---------------- fused cooperative kernel ----------------
__global__ __launch_bounds__(256, 3) void k_fused(
    const float* __restrict__ A, const float* __restrict__ C,
    const float* __restrict__ W, const float* __restrict__ V,
    const int* __restrict__ n1, const int* __restrict__ n2,
    unsigned short* __restrict__ Qimg, float* __restrict__ G,
    float* __restrict__ Out) {
    __shared__ SMem sm;
    const int tid = threadIdx.x;
    cg::grid_group grid = cg::this_grid();

    // phase 0: prep (blocks 0..15)
    if (blockIdx.x < 16) {
        prep_body(sm.p, blockIdx.x, tid, C, W, V, Qimg);
        __threadfence();
    }
    grid.sync();

    // phase 1: gemm, grid-stride over tiles
    bool first = true;
    for (int tile = blockIdx.x; tile < NTILES; tile += gridDim.x) {
        gemm_tile(sm.m, tile, first, tid, A, Qimg, G);
        first = false;
    }
    __threadfence();
    grid.sync();

    // phase 2: epilogue, grid-stride over rows
    for (long i = (long)blockIdx.x * 256 + tid; i < NROWS; i += (long)gridDim.x * 256)
        epi_row(i, G, n1, n2, Out);
}

// ---------------- fallback (r9) kernels ----------------
__global__ __launch_bounds__(256) void k_prep(
    const float* __restrict__ C, const float* __restrict__ W, const float* __restrict__ V,
    unsigned short* __restrict__ Qimg) {
    __shared__ PrepSm sm;
    prep_body(sm, blockIdx.x, threadIdx.x, C, W, V, Qimg);
}

__global__ __launch_bounds__(256, 3) void k_gemm(
    const float* __restrict__ A, const unsigned short* __restrict__ Qimg,
    float* __restrict__ G) {
    __shared__ MainSm sm;
    gemm_tile(sm, blockIdx.x, true, threadIdx.x, A, Qimg, G);
}

__global__ __launch_bounds__(256) void k_epi(
    const float* __restrict__ G,
    const int* __restrict__ n1, const int* __restrict__ n2,
    float* __restrict__ Out) {
    const long i = (long)blockIdx.x * 256 + threadIdx.x;
    if (i < NROWS) epi_row(i, G, n1, n2, Out);
}

extern "C" void kernel_launch(void* const* d_in, const int* in_sizes, int n_in,
                              void* d_out, int out_size, void* d_ws, size_t ws_size,
                              hipStream_t stream) {
    const float* features = (const float*)d_in[0];
    const float* C  = (const float*)d_in[1];
    const float* W  = (const float*)d_in[2];
    const float* V  = (const float*)d_in[3];
    const int*   n1 = (const int*)d_in[4];
    const int*   n2 = (const int*)d_in[5];
    float* out = (float*)d_out;

    char* ws = (char*)d_ws;
    unsigned short* Qimg = (unsigned short*)ws;   // 32 KB
    float* G = (float*)(ws + 32768);              // 100000*24*4 = 9.6 MB

    int coop = 0, dev = 0;
    hipGetDevice(&dev);
    hipDeviceGetAttribute(&coop, hipDeviceAttributeCooperativeLaunch, dev);
    int nb = 0;
    if (coop &&
        hipOccupancyMaxActiveBlocksPerMultiprocessor(&nb, k_fused, 256, 0) == hipSuccess &&
        nb >= 1) {
        int grid = nb * 256;
        if (grid > NTILES) grid = NTILES;
        void* args[9] = {(void*)&features, (void*)&C, (void*)&W, (void*)&V,
                         (void*)&n1, (void*)&n2, (void*)&Qimg, (void*)&G, (void*)&out};
        if (hipLaunchCooperativeKernel((const void*)k_fused, dim3(grid), dim3(256),
                                       args, 0, stream) == hipSuccess)
            return;
    }
    // fallback: r9 three-kernel path
    hipLaunchKernelGGL(k_prep, dim3(16), dim3(256), 0, stream, C, W, V, Qimg);
    hipLaunchKernelGGL(k_gemm, dim3(NTILES), dim3(256), 0, stream, features, Qimg, G);
    hipLaunchKernelGGL(k_epi, dim3((NROWS + 255) / 256), dim3(256), 0, stream,
                       G, n1, n2, out);
}

// Round 13
// 65.018 us; speedup vs baseline: 2.4339x; 2.4339x over previous
//
#include <hip/hip_runtime.h>
#include <hip/hip_bf16.h>
#include <stdint.h>

#define NROWS 100000
#define INDIM 512
#define HID 128
#define NCLS 10
#define LEAKY_ALPHA 0.2f
#define GSTR 24   // G row stride (f32)

typedef __bf16 bf16x8_t __attribute__((ext_vector_type(8)));
typedef __bf16 bf16x4_t __attribute__((ext_vector_type(4)));
typedef float f32x4_t __attribute__((ext_vector_type(4)));
typedef unsigned short ushort8_t __attribute__((ext_vector_type(8)));

union Frag {
    bf16x8_t v8;
    bf16x4_t v4[2];
    unsigned short u[8];
};

__device__ __forceinline__ unsigned short f2bf(float x) {
    union { __hip_bfloat16 b; unsigned short u; } cv;
    cv.b = __float2bfloat16(x);
    return cv.u;
}

// Byte address inside an [R x 32] bf16 tile image (rows paired into 128-B
// lines, 16-B units XOR-swizzled by pair&7). Bank-verified round 3; r12 PMC
// confirmed conflicts are negligible (0.7%).
__device__ __forceinline__ int img_addr(int r, int kk) {
    int p = r >> 1;
    int o = ((r & 1) << 6) | (kk << 1);
    return (p << 7) | ((((o >> 4) ^ (p & 7)) << 4) | (o & 15));
}

__device__ __forceinline__ void gload_lds16(const void* g, void* l) {
    __builtin_amdgcn_global_load_lds(
        (const __attribute__((address_space(1))) unsigned int*)g,
        (__attribute__((address_space(3))) unsigned int*)l, 16, 0, 0);
}

// ---------------- prep: Qimg = swizzled tile images of Q = [C@(W1@V) | C@(W2@V)] ----------------
__global__ __launch_bounds__(256) void k_prep(
    const float* __restrict__ C, const float* __restrict__ W, const float* __restrict__ V,
    unsigned short* __restrict__ Qimg) {
    __shared__ float Vl[HID * NCLS];
    __shared__ float Pl[2][HID][10];
    __shared__ float Cl[32][132];

    const int tid = threadIdx.x, b = blockIdx.x;
    for (int i = tid; i < HID * NCLS; i += 256) Vl[i] = V[i];
    __syncthreads();

    {
        const int half = tid >> 7, j = tid & 127;
        const float* wr = W + (half * HID + j) * HID;
        float s[NCLS];
#pragma unroll
        for (int c = 0; c < NCLS; ++c) s[c] = 0.f;
        for (int m = 0; m < HID; m += 4) {
            float4 wv = *reinterpret_cast<const float4*>(wr + m);
            float wa[4] = {wv.x, wv.y, wv.z, wv.w};
#pragma unroll
            for (int u = 0; u < 4; ++u)
#pragma unroll
                for (int c = 0; c < NCLS; ++c) s[c] += wa[u] * Vl[(m + u) * NCLS + c];
        }
#pragma unroll
        for (int c = 0; c < NCLS; ++c) Pl[half][j][c] = s[c];
    }
    const int k0 = b << 5;
    {
        const int kr = tid >> 3, ns = (tid & 7) << 4;
        const float4* src = reinterpret_cast<const float4*>(C + (k0 + kr) * HID + ns);
#pragma unroll
        for (int j = 0; j < 4; ++j)
            *reinterpret_cast<float4*>(&Cl[kr][ns + 4 * j]) = src[j];
    }
    __syncthreads();

    for (int e = tid; e < 32 * 32; e += 256) {
        const int n = e >> 5, kl = e & 31;
        const int half = n >> 4, c = n & 15;
        float s = 0.f;
        if (c < NCLS) {
#pragma unroll 4
            for (int j = 0; j < HID; ++j) s += Cl[kl][j] * Pl[half][j][c];
        }
        *(unsigned short*)((char*)Qimg + b * 2048 + img_addr(n, kl)) = f2bf(s);
    }
}

// ---------------- thin GEMM: g = f @ Q  (r9 structure @ 4 blocks/CU) ----------------
// BM=128, 4 waves. Wave-private SINGLE-buffer A staging (8 KB; safe: same-wave
// in-order DS, barrier-free loop). Depth-2 register queue (refill t+3).
// LDS 40 KB -> 4 blocks/CU = 16 waves (the isolated occupancy lever).
__global__ __launch_bounds__(256, 4) void k_gemm(
    const float* __restrict__ A,             // [NROWS][512] f32
    const unsigned short* __restrict__ Qimg, // 16 x 2KB swizzled tile images
    float* __restrict__ G)                   // [NROWS][GSTR] f32
{
    __shared__ unsigned short Qs[16384];     // 32 KB
    __shared__ unsigned short As[4096];      // 8 KB single buffer

    const int tid  = threadIdx.x;
    const int w    = tid >> 6;
    const int lane = tid & 63;
    const int l15  = lane & 15;
    const int kg   = (lane >> 4) << 2;
    const long row0 = (long)blockIdx.x * 128;

    // stage all of Q once (wave-uniform dests)
#pragma unroll
    for (int j = 0; j < 8; ++j) {
        const int off = (j * 4 + w) * 1024;
        gload_lds16((const char*)Qimg + off + lane * 16, (char*)Qs + off);
    }

    // A staging: thread -> (row tid>>1, 16-float half); wave-private rows
    const int ar_s = tid >> 1;
    const int kh   = (tid & 1) << 4;
    long gr = row0 + ar_s;
    if (gr >= NROWS) gr = NROWS - 1;
    const float* asrc = A + gr * INDIM + kh;
    const int aw0 = img_addr(ar_s, kh);
    const int aw1 = img_addr(ar_s, kh + 8);

    int ard0[2], ard1[2], brd0[2], brd1[2];
#pragma unroll
    for (int ii = 0; ii < 2; ++ii) {
        int r = w * 32 + ii * 16 + l15;
        ard0[ii] = img_addr(r, kg);
        ard1[ii] = img_addr(r, kg + 16);
    }
#pragma unroll
    for (int f = 0; f < 2; ++f) {
        brd0[f] = img_addr(f * 16 + l15, kg);
        brd1[f] = img_addr(f * 16 + l15, kg + 16);
    }

    f32x4_t acc[2][2];
#pragma unroll
    for (int i = 0; i < 2; ++i)
#pragma unroll
        for (int f = 0; f < 2; ++f)
#pragma unroll
            for (int r = 0; r < 4; ++r) acc[i][f][r] = 0.f;

    const char* asb = (const char*)&As[0];
    const char* bsb = (const char*)&Qs[0];

    float4 qA[4], qB[4];   // chunk c lives in slot c&1 (static names)

    // prologue: chunk 0 staged directly; chunk 1 -> qB, chunk 2 -> qA
    {
        float4 v[4];
#pragma unroll
        for (int j = 0; j < 4; ++j) v[j] = *reinterpret_cast<const float4*>(asrc + 4 * j);
        ushort8_t lo, hi;
#pragma unroll
        for (int e = 0; e < 4; ++e) {
            lo[e] = f2bf(v[0][e]); lo[4 + e] = f2bf(v[1][e]);
            hi[e] = f2bf(v[2][e]); hi[4 + e] = f2bf(v[3][e]);
        }
        *(ushort8_t*)((char*)asb + aw0) = lo;
        *(ushort8_t*)((char*)asb + aw1) = hi;
    }
#pragma unroll
    for (int j = 0; j < 4; ++j) qB[j] = *reinterpret_cast<const float4*>(asrc + 32 + 4 * j);
#pragma unroll
    for (int j = 0; j < 4; ++j) qA[j] = *reinterpret_cast<const float4*>(asrc + 64 + 4 * j);
    __syncthreads();   // the ONLY barrier: Q visible to all waves

#pragma unroll
    for (int t = 0; t < 16; ++t) {
        Frag fa[2], fb[2];
#pragma unroll
        for (int ii = 0; ii < 2; ++ii) {
            fa[ii].v4[0] = *(const bf16x4_t*)(asb + ard0[ii]);
            fa[ii].v4[1] = *(const bf16x4_t*)(asb + ard1[ii]);
        }
#pragma unroll
        for (int f = 0; f < 2; ++f) {
            fb[f].v4[0] = *(const bf16x4_t*)(bsb + t * 2048 + brd0[f]);
            fb[f].v4[1] = *(const bf16x4_t*)(bsb + t * 2048 + brd1[f]);
        }
#pragma unroll
        for (int ii = 0; ii < 2; ++ii)
#pragma unroll
            for (int f = 0; f < 2; ++f)
                acc[ii][f] = __builtin_amdgcn_mfma_f32_16x16x32_bf16(fa[ii].v8, fb[f].v8, acc[ii][f], 0, 0, 0);

        if (t < 15) {
            // convert chunk t+1 (slot (t+1)&1), overwrite the single buffer:
            // program-order after this iter's fa reads; in-order DS pipe
            // guarantees next iter's reads see it. Wave-private -> race-free.
            const int slot = (t + 1) & 1;
            ushort8_t lo, hi;
            if (slot == 1) {
#pragma unroll
                for (int e = 0; e < 4; ++e) {
                    lo[e] = f2bf(qB[0][e]); lo[4 + e] = f2bf(qB[1][e]);
                    hi[e] = f2bf(qB[2][e]); hi[4 + e] = f2bf(qB[3][e]);
                }
            } else {
#pragma unroll
                for (int e = 0; e < 4; ++e) {
                    lo[e] = f2bf(qA[0][e]); lo[4 + e] = f2bf(qA[1][e]);
                    hi[e] = f2bf(qA[2][e]); hi[4 + e] = f2bf(qA[3][e]);
                }
            }
            *(ushort8_t*)((char*)asb + aw0) = lo;
            *(ushort8_t*)((char*)asb + aw1) = hi;

            // refill the just-freed slot with chunk t+3
            if (t + 3 <= 15) {
                const float* src = asrc + (t + 3) * 32;
                if (slot == 1) {
#pragma unroll
                    for (int j = 0; j < 4; ++j) qB[j] = *reinterpret_cast<const float4*>(src + 4 * j);
                } else {
#pragma unroll
                    for (int j = 0; j < 4; ++j) qA[j] = *reinterpret_cast<const float4*>(src + 4 * j);
                }
            }
        }
    }

    // epilogue: G[row][l15] = f@Q1, G[row][12+l15] = f@Q2
    const int rq_ = (lane >> 4) << 2;
#pragma unroll
    for (int ii = 0; ii < 2; ++ii)
#pragma unroll
        for (int r = 0; r < 4; ++r) {
            long grow = row0 + w * 32 + ii * 16 + rq_ + r;
            if (l15 < NCLS && grow < NROWS) {
                G[grow * GSTR + l15]      = acc[ii][0][r];
                G[grow * GSTR + 12 + l15] = acc[ii][1][r];
            }
        }
}

// ---------------- epilogue: logits = leaky(g[n1][0:10] + g[n2][12:22]), log_softmax ----------------
__global__ __launch_bounds__(256) void k_epi(
    const float* __restrict__ G,
    const int* __restrict__ n1, const int* __restrict__ n2,
    float* __restrict__ Out) {
    const long i = (long)blockIdx.x * 256 + threadIdx.x;
    if (i >= NROWS) return;
    const float* g1 = G + (long)n1[i] * GSTR;
    const float* g2 = G + (long)n2[i] * GSTR + 12;

    float4 a0 = *(const float4*)(g1);
    float4 a1 = *(const float4*)(g1 + 4);
    float2 a2 = *(const float2*)(g1 + 8);
    float4 b0 = *(const float4*)(g2);
    float4 b1 = *(const float4*)(g2 + 4);
    float2 b2 = *(const float2*)(g2 + 8);

    float x[NCLS] = {a0.x + b0.x, a0.y + b0.y, a0.z + b0.z, a0.w + b0.w,
                     a1.x + b1.x, a1.y + b1.y, a1.z + b1.z, a1.w + b1.w,
                     a2.x + b2.x, a2.y + b2.y};
    float m = -1e30f;
#pragma unroll
    for (int c = 0; c < NCLS; ++c) {
        x[c] = (x[c] >= 0.f) ? x[c] : LEAKY_ALPHA * x[c];
        m = fmaxf(m, x[c]);
    }
    float sum = 0.f;
#pragma unroll
    for (int c = 0; c < NCLS; ++c) sum += __expf(x[c] - m);
    const float lse = m + __logf(sum);
    float2* o = (float2*)(Out + i * NCLS);
#pragma unroll
    for (int j = 0; j < 5; ++j) {
        float2 v = {x[2 * j] - lse, x[2 * j + 1] - lse};
        o[j] = v;
    }
}

extern "C" void kernel_launch(void* const* d_in, const int* in_sizes, int n_in,
                              void* d_out, int out_size, void* d_ws, size_t ws_size,
                              hipStream_t stream) {
    const float* features = (const float*)d_in[0];
    const float* C  = (const float*)d_in[1];
    const float* W  = (const float*)d_in[2];
    const float* V  = (const float*)d_in[3];
    const int*   n1 = (const int*)d_in[4];
    const int*   n2 = (const int*)d_in[5];
    float* out = (float*)d_out;

    char* ws = (char*)d_ws;
    unsigned short* Qimg = (unsigned short*)ws;   // 32 KB
    float* G = (float*)(ws + 32768);              // 100000*24*4 = 9.6 MB

    hipLaunchKernelGGL(k_prep, dim3(16), dim3(256), 0, stream, C, W, V, Qimg);
    hipLaunchKernelGGL(k_gemm, dim3((NROWS + 127) / 128), dim3(256), 0, stream,
                       features, Qimg, G);
    hipLaunchKernelGGL(k_epi, dim3((NROWS + 255) / 256), dim3(256), 0, stream,
                       G, n1, n2, out);
}

// Round 14
// 62.119 us; speedup vs baseline: 2.5475x; 1.0467x over previous
//
#include <hip/hip_runtime.h>
#include <hip/hip_bf16.h>
#include <stdint.h>

#define NROWS 100000
#define INDIM 512
#define HID 128
#define NCLS 10
#define LEAKY_ALPHA 0.2f
#define GSTR 24   // G row stride (f32)

typedef __bf16 bf16x8_t __attribute__((ext_vector_type(8)));
typedef __bf16 bf16x4_t __attribute__((ext_vector_type(4)));
typedef float f32x4_t __attribute__((ext_vector_type(4)));
typedef unsigned short ushort4_t __attribute__((ext_vector_type(4)));
typedef unsigned short ushort8_t __attribute__((ext_vector_type(8)));

union Frag {
    bf16x8_t v8;
    bf16x4_t v4[2];
    unsigned short u[8];
};

__device__ __forceinline__ unsigned short f2bf(float x) {
    union { __hip_bfloat16 b; unsigned short u; } cv;
    cv.b = __float2bfloat16(x);
    return cv.u;
}

// Byte address inside an [R x 32] bf16 tile image (rows paired into 128-B
// lines, 16-B units XOR-swizzled by pair&7). Bank-verified round 3; r12 PMC
// confirmed conflicts negligible. A ushort4 at kk in {0,4,...,28} stays
// within one 16-B unit -> contiguous 8-B store.
__device__ __forceinline__ int img_addr(int r, int kk) {
    int p = r >> 1;
    int o = ((r & 1) << 6) | (kk << 1);
    return (p << 7) | ((((o >> 4) ^ (p & 7)) << 4) | (o & 15));
}

__device__ __forceinline__ void gload_lds16(const void* g, void* l) {
    __builtin_amdgcn_global_load_lds(
        (const __attribute__((address_space(1))) unsigned int*)g,
        (__attribute__((address_space(3))) unsigned int*)l, 16, 0, 0);
}

// ---------------- prep: Qimg = swizzled tile images of Q = [C@(W1@V) | C@(W2@V)] ----------------
__global__ __launch_bounds__(256) void k_prep(
    const float* __restrict__ C, const float* __restrict__ W, const float* __restrict__ V,
    unsigned short* __restrict__ Qimg) {
    __shared__ float Vl[HID * NCLS];
    __shared__ float Pl[2][HID][10];
    __shared__ float Cl[32][132];

    const int tid = threadIdx.x, b = blockIdx.x;
    for (int i = tid; i < HID * NCLS; i += 256) Vl[i] = V[i];
    __syncthreads();

    {
        const int half = tid >> 7, j = tid & 127;
        const float* wr = W + (half * HID + j) * HID;
        float s[NCLS];
#pragma unroll
        for (int c = 0; c < NCLS; ++c) s[c] = 0.f;
        for (int m = 0; m < HID; m += 4) {
            float4 wv = *reinterpret_cast<const float4*>(wr + m);
            float wa[4] = {wv.x, wv.y, wv.z, wv.w};
#pragma unroll
            for (int u = 0; u < 4; ++u)
#pragma unroll
                for (int c = 0; c < NCLS; ++c) s[c] += wa[u] * Vl[(m + u) * NCLS + c];
        }
#pragma unroll
        for (int c = 0; c < NCLS; ++c) Pl[half][j][c] = s[c];
    }
    const int k0 = b << 5;
    {
        const int kr = tid >> 3, ns = (tid & 7) << 4;
        const float4* src = reinterpret_cast<const float4*>(C + (k0 + kr) * HID + ns);
#pragma unroll
        for (int j = 0; j < 4; ++j)
            *reinterpret_cast<float4*>(&Cl[kr][ns + 4 * j]) = src[j];
    }
    __syncthreads();

    for (int e = tid; e < 32 * 32; e += 256) {
        const int n = e >> 5, kl = e & 31;
        const int half = n >> 4, c = n & 15;
        float s = 0.f;
        if (c < NCLS) {
#pragma unroll 4
            for (int j = 0; j < HID; ++j) s += Cl[kl][j] * Pl[half][j][c];
        }
        *(unsigned short*)((char*)Qimg + b * 2048 + img_addr(n, kl)) = f2bf(s);
    }
}

// ---------------- thin GEMM: g = f @ Q  (coalesced lane-along-k staging) ----------------
// BM=128, 4 waves. A-staging remapped: wave w, pass j in 0..3 -> rows
// 32w+8j+(lane>>3), bytes (lane&7)*16: each wave instruction covers 8 FULL
// 128-B lines (was 32 x 32-B partial lines) -> 4x fewer memory requests,
// full-line DRAM granularity. Wave-private rows preserved -> barrier-free
// single-buffer loop (r13 structure). Depth-2 register queue. 40 KB LDS.
__global__ __launch_bounds__(256, 4) void k_gemm(
    const float* __restrict__ A,             // [NROWS][512] f32
    const unsigned short* __restrict__ Qimg, // 16 x 2KB swizzled tile images
    float* __restrict__ G)                   // [NROWS][GSTR] f32
{
    __shared__ unsigned short Qs[16384];     // 32 KB
    __shared__ unsigned short As[4096];      // 8 KB single buffer

    const int tid  = threadIdx.x;
    const int w    = tid >> 6;
    const int lane = tid & 63;
    const int l15  = lane & 15;
    const int kg   = (lane >> 4) << 2;
    const long row0 = (long)blockIdx.x * 128;

    // stage all of Q once (wave-uniform dests)
#pragma unroll
    for (int j = 0; j < 8; ++j) {
        const int off = (j * 4 + w) * 1024;
        gload_lds16((const char*)Qimg + off + lane * 16, (char*)Qs + off);
    }

    // A staging: pass j -> local row 32w + 8j + (lane>>3), float seg (lane&7)*4
    const int kseg = (lane & 7) << 2;        // float index within 32-float chunk
    const float* asrc_[4];
    int awr_[4];
#pragma unroll
    for (int j = 0; j < 4; ++j) {
        const int lr = w * 32 + j * 8 + (lane >> 3);
        long gr = row0 + lr;
        if (gr >= NROWS) gr = NROWS - 1;
        asrc_[j] = A + gr * INDIM + kseg;
        awr_[j] = img_addr(lr, kseg);
    }

    int ard0[2], ard1[2], brd0[2], brd1[2];
#pragma unroll
    for (int ii = 0; ii < 2; ++ii) {
        int r = w * 32 + ii * 16 + l15;
        ard0[ii] = img_addr(r, kg);
        ard1[ii] = img_addr(r, kg + 16);
    }
#pragma unroll
    for (int f = 0; f < 2; ++f) {
        brd0[f] = img_addr(f * 16 + l15, kg);
        brd1[f] = img_addr(f * 16 + l15, kg + 16);
    }

    f32x4_t acc[2][2];
#pragma unroll
    for (int i = 0; i < 2; ++i)
#pragma unroll
        for (int f = 0; f < 2; ++f)
#pragma unroll
            for (int r = 0; r < 4; ++r) acc[i][f][r] = 0.f;

    const char* asb = (const char*)&As[0];
    const char* bsb = (const char*)&Qs[0];

    float4 qA[4], qB[4];   // chunk c lives in slot c&1; element j = pass j

    // prologue: chunk 0 staged directly; chunk 1 -> qB, chunk 2 -> qA
    {
        float4 v[4];
#pragma unroll
        for (int j = 0; j < 4; ++j) v[j] = *reinterpret_cast<const float4*>(asrc_[j]);
#pragma unroll
        for (int j = 0; j < 4; ++j) {
            ushort4_t pk;
#pragma unroll
            for (int e = 0; e < 4; ++e) pk[e] = f2bf(v[j][e]);
            *(ushort4_t*)((char*)asb + awr_[j]) = pk;
        }
    }
#pragma unroll
    for (int j = 0; j < 4; ++j) qB[j] = *reinterpret_cast<const float4*>(asrc_[j] + 32);
#pragma unroll
    for (int j = 0; j < 4; ++j) qA[j] = *reinterpret_cast<const float4*>(asrc_[j] + 64);
    __syncthreads();   // the ONLY barrier: Q visible to all waves

#pragma unroll
    for (int t = 0; t < 16; ++t) {
        Frag fa[2], fb[2];
#pragma unroll
        for (int ii = 0; ii < 2; ++ii) {
            fa[ii].v4[0] = *(const bf16x4_t*)(asb + ard0[ii]);
            fa[ii].v4[1] = *(const bf16x4_t*)(asb + ard1[ii]);
        }
#pragma unroll
        for (int f = 0; f < 2; ++f) {
            fb[f].v4[0] = *(const bf16x4_t*)(bsb + t * 2048 + brd0[f]);
            fb[f].v4[1] = *(const bf16x4_t*)(bsb + t * 2048 + brd1[f]);
        }
#pragma unroll
        for (int ii = 0; ii < 2; ++ii)
#pragma unroll
            for (int f = 0; f < 2; ++f)
                acc[ii][f] = __builtin_amdgcn_mfma_f32_16x16x32_bf16(fa[ii].v8, fb[f].v8, acc[ii][f], 0, 0, 0);

        if (t < 15) {
            // convert chunk t+1 (slot (t+1)&1), overwrite single buffer:
            // program-order after this iter's fa reads; same-wave in-order DS
            // + wave-private rows -> race-free without barriers.
            const int slot = (t + 1) & 1;
            if (slot == 1) {
#pragma unroll
                for (int j = 0; j < 4; ++j) {
                    ushort4_t pk;
#pragma unroll
                    for (int e = 0; e < 4; ++e) pk[e] = f2bf(qB[j][e]);
                    *(ushort4_t*)((char*)asb + awr_[j]) = pk;
                }
            } else {
#pragma unroll
                for (int j = 0; j < 4; ++j) {
                    ushort4_t pk;
#pragma unroll
                    for (int e = 0; e < 4; ++e) pk[e] = f2bf(qA[j][e]);
                    *(ushort4_t*)((char*)asb + awr_[j]) = pk;
                }
            }

            // refill the just-freed slot with chunk t+3
            if (t + 3 <= 15) {
                const int off = (t + 3) * 32;
                if (slot == 1) {
#pragma unroll
                    for (int j = 0; j < 4; ++j) qB[j] = *reinterpret_cast<const float4*>(asrc_[j] + off);
                } else {
#pragma unroll
                    for (int j = 0; j < 4; ++j) qA[j] = *reinterpret_cast<const float4*>(asrc_[j] + off);
                }
            }
        }
    }

    // epilogue: G[row][l15] = f@Q1, G[row][12+l15] = f@Q2
    const int rq_ = (lane >> 4) << 2;
#pragma unroll
    for (int ii = 0; ii < 2; ++ii)
#pragma unroll
        for (int r = 0; r < 4; ++r) {
            long grow = row0 + w * 32 + ii * 16 + rq_ + r;
            if (l15 < NCLS && grow < NROWS) {
                G[grow * GSTR + l15]      = acc[ii][0][r];
                G[grow * GSTR + 12 + l15] = acc[ii][1][r];
            }
        }
}

// ---------------- epilogue: logits = leaky(g[n1][0:10] + g[n2][12:22]), log_softmax ----------------
__global__ __launch_bounds__(256) void k_epi(
    const float* __restrict__ G,
    const int* __restrict__ n1, const int* __restrict__ n2,
    float* __restrict__ Out) {
    const long i = (long)blockIdx.x * 256 + threadIdx.x;
    if (i >= NROWS) return;
    const float* g1 = G + (long)n1[i] * GSTR;
    const float* g2 = G + (long)n2[i] * GSTR + 12;

    float4 a0 = *(const float4*)(g1);
    float4 a1 = *(const float4*)(g1 + 4);
    float2 a2 = *(const float2*)(g1 + 8);
    float4 b0 = *(const float4*)(g2);
    float4 b1 = *(const float4*)(g2 + 4);
    float2 b2 = *(const float2*)(g2 + 8);

    float x[NCLS] = {a0.x + b0.x, a0.y + b0.y, a0.z + b0.z, a0.w + b0.w,
                     a1.x + b1.x, a1.y + b1.y, a1.z + b1.z, a1.w + b1.w,
                     a2.x + b2.x, a2.y + b2.y};
    float m = -1e30f;
#pragma unroll
    for (int c = 0; c < NCLS; ++c) {
        x[c] = (x[c] >= 0.f) ? x[c] : LEAKY_ALPHA * x[c];
        m = fmaxf(m, x[c]);
    }
    float sum = 0.f;
#pragma unroll
    for (int c = 0; c < NCLS; ++c) sum += __expf(x[c] - m);
    const float lse = m + __logf(sum);
    float2* o = (float2*)(Out + i * NCLS);
#pragma unroll
    for (int j = 0; j < 5; ++j) {
        float2 v = {x[2 * j] - lse, x[2 * j + 1] - lse};
        o[j] = v;
    }
}

extern "C" void kernel_launch(void* const* d_in, const int* in_sizes, int n_in,
                              void* d_out, int out_size, void* d_ws, size_t ws_size,
                              hipStream_t stream) {
    const float* features = (const float*)d_in[0];
    const float* C  = (const float*)d_in[1];
    const float* W  = (const float*)d_in[2];
    const float* V  = (const float*)d_in[3];
    const int*   n1 = (const int*)d_in[4];
    const int*   n2 = (const int*)d_in[5];
    float* out = (float*)d_out;

    char* ws = (char*)d_ws;
    unsigned short* Qimg = (unsigned short*)ws;   // 32 KB
    float* G = (float*)(ws + 32768);              // 100000*24*4 = 9.6 MB

    hipLaunchKernelGGL(k_prep, dim3(16), dim3(256), 0, stream, C, W, V, Qimg);
    hipLaunchKernelGGL(k_gemm, dim3((NROWS + 127) / 128), dim3(256), 0, stream,
                       features, Qimg, G);
    hipLaunchKernelGGL(k_epi, dim3((NROWS + 255) / 256), dim3(256), 0, stream,
                       G, n1, n2, out);
}

// Round 15
// 57.763 us; speedup vs baseline: 2.7396x; 1.0754x over previous
//
#include <hip/hip_runtime.h>
#include <hip/hip_bf16.h>
#include <stdint.h>

#define NROWS 100000
#define INDIM 512
#define HID 128
#define NCLS 10
#define LEAKY_ALPHA 0.2f
#define GSTR 24   // G row stride (f32)

typedef __bf16 bf16x8_t __attribute__((ext_vector_type(8)));
typedef __bf16 bf16x4_t __attribute__((ext_vector_type(4)));
typedef float f32x4_t __attribute__((ext_vector_type(4)));
typedef unsigned short ushort4_t __attribute__((ext_vector_type(4)));
typedef unsigned short ushort8_t __attribute__((ext_vector_type(8)));

union Frag {
    bf16x8_t v8;
    bf16x4_t v4[2];
    unsigned short u[8];
};

__device__ __forceinline__ unsigned short f2bf(float x) {
    union { __hip_bfloat16 b; unsigned short u; } cv;
    cv.b = __float2bfloat16(x);
    return cv.u;
}

// Byte address inside an [R x 32] bf16 tile image (rows paired into 128-B
// lines, 16-B units XOR-swizzled by pair&7). Bank-verified round 3; r12 PMC
// confirmed conflicts negligible.
__device__ __forceinline__ int img_addr(int r, int kk) {
    int p = r >> 1;
    int o = ((r & 1) << 6) | (kk << 1);
    return (p << 7) | ((((o >> 4) ^ (p & 7)) << 4) | (o & 15));
}

__device__ __forceinline__ void gload_lds16(const void* g, void* l) {
    __builtin_amdgcn_global_load_lds(
        (const __attribute__((address_space(1))) unsigned int*)g,
        (__attribute__((address_space(3))) unsigned int*)l, 16, 0, 0);
}

// ---------------- prep: Qimg = swizzled tile images of Q = [C@(W1@V) | C@(W2@V)] ----------------
// 64 blocks; block b produces k-rows [b*8, b*8+8). P = W@V recomputed per
// block (redundant but cheap: W is L2-resident after first touch).
__global__ __launch_bounds__(256) void k_prep(
    const float* __restrict__ C, const float* __restrict__ W, const float* __restrict__ V,
    unsigned short* __restrict__ Qimg) {
    __shared__ float Vl[HID * NCLS];
    __shared__ float Pl[2][HID][10];
    __shared__ float Cl[8][132];

    const int tid = threadIdx.x, b = blockIdx.x;
    for (int i = tid; i < HID * NCLS; i += 256) Vl[i] = V[i];
    __syncthreads();

    // P[half][j][c] = dot(W[half*128 + j, :], V[:, c])
    {
        const int half = tid >> 7, j = tid & 127;
        const float* wr = W + (half * HID + j) * HID;
        float s[NCLS];
#pragma unroll
        for (int c = 0; c < NCLS; ++c) s[c] = 0.f;
        for (int m = 0; m < HID; m += 4) {
            float4 wv = *reinterpret_cast<const float4*>(wr + m);
            float wa[4] = {wv.x, wv.y, wv.z, wv.w};
#pragma unroll
            for (int u = 0; u < 4; ++u)
#pragma unroll
                for (int c = 0; c < NCLS; ++c) s[c] += wa[u] * Vl[(m + u) * NCLS + c];
        }
#pragma unroll
        for (int c = 0; c < NCLS; ++c) Pl[half][j][c] = s[c];
    }
    // stage C rows [k0, k0+8)
    const int k0 = b << 3;
    if (tid < 256) {
        const int kr = tid >> 5, ns = (tid & 31) << 2;
        *reinterpret_cast<float4*>(&Cl[kr][ns]) =
            *reinterpret_cast<const float4*>(C + (k0 + kr) * HID + ns);
    }
    __syncthreads();

    // Q entries: 8 k x 32 n = 256 -> one per thread
    {
        const int n = tid >> 3, kl = tid & 7;
        const int half = n >> 4, c = n & 15;
        float s = 0.f;
        if (c < NCLS) {
#pragma unroll 4
            for (int j = 0; j < HID; ++j) s += Cl[kl][j] * Pl[half][j][c];
        }
        const int k = k0 + kl, t = k >> 5, kk = k & 31;
        *(unsigned short*)((char*)Qimg + t * 2048 + img_addr(n, kk)) = f2bf(s);
    }
}

// ---------------- thin GEMM: g = f @ Q  (coalesced staging + depth-3 queue @ 4 blk/CU) ----------------
// BM=128, 4 waves. Lane-along-k staging (r14: full 128-B-line wave requests),
// wave-private rows -> barrier-free single-buffer loop, depth-3 register
// queue (chunk c in slot c%3, refill t+4 = 3 iters of HBM cover, 12
// outstanding loads/thread). LDS 40 KB -> 4 blocks/CU.
__global__ __launch_bounds__(256, 4) void k_gemm(
    const float* __restrict__ A,             // [NROWS][512] f32
    const unsigned short* __restrict__ Qimg, // 16 x 2KB swizzled tile images
    float* __restrict__ G)                   // [NROWS][GSTR] f32
{
    __shared__ unsigned short Qs[16384];     // 32 KB
    __shared__ unsigned short As[4096];      // 8 KB single buffer

    const int tid  = threadIdx.x;
    const int w    = tid >> 6;
    const int lane = tid & 63;
    const int l15  = lane & 15;
    const int kg   = (lane >> 4) << 2;
    const long row0 = (long)blockIdx.x * 128;

    // stage all of Q once (wave-uniform dests)
#pragma unroll
    for (int j = 0; j < 8; ++j) {
        const int off = (j * 4 + w) * 1024;
        gload_lds16((const char*)Qimg + off + lane * 16, (char*)Qs + off);
    }

    // A staging: pass j -> local row 32w + 8j + (lane>>3), float seg (lane&7)*4
    const int kseg = (lane & 7) << 2;
    const float* asrc_[4];
    int awr_[4];
#pragma unroll
    for (int j = 0; j < 4; ++j) {
        const int lr = w * 32 + j * 8 + (lane >> 3);
        long gr = row0 + lr;
        if (gr >= NROWS) gr = NROWS - 1;
        asrc_[j] = A + gr * INDIM + kseg;
        awr_[j] = img_addr(lr, kseg);
    }

    int ard0[2], ard1[2], brd0[2], brd1[2];
#pragma unroll
    for (int ii = 0; ii < 2; ++ii) {
        int r = w * 32 + ii * 16 + l15;
        ard0[ii] = img_addr(r, kg);
        ard1[ii] = img_addr(r, kg + 16);
    }
#pragma unroll
    for (int f = 0; f < 2; ++f) {
        brd0[f] = img_addr(f * 16 + l15, kg);
        brd1[f] = img_addr(f * 16 + l15, kg + 16);
    }

    f32x4_t acc[2][2];
#pragma unroll
    for (int i = 0; i < 2; ++i)
#pragma unroll
        for (int f = 0; f < 2; ++f)
#pragma unroll
            for (int r = 0; r < 4; ++r) acc[i][f][r] = 0.f;

    const char* asb = (const char*)&As[0];
    const char* bsb = (const char*)&Qs[0];

    float4 qA[4], qB[4], qC[4];   // chunk c lives in slot c%3 (static names)

    // prologue: chunk 0 staged directly; chunks 1,2,3 -> slots 1,2,0
    {
        float4 v[4];
#pragma unroll
        for (int j = 0; j < 4; ++j) v[j] = *reinterpret_cast<const float4*>(asrc_[j]);
#pragma unroll
        for (int j = 0; j < 4; ++j) {
            ushort4_t pk;
#pragma unroll
            for (int e = 0; e < 4; ++e) pk[e] = f2bf(v[j][e]);
            *(ushort4_t*)((char*)asb + awr_[j]) = pk;
        }
    }
#pragma unroll
    for (int j = 0; j < 4; ++j) qB[j] = *reinterpret_cast<const float4*>(asrc_[j] + 32);
#pragma unroll
    for (int j = 0; j < 4; ++j) qC[j] = *reinterpret_cast<const float4*>(asrc_[j] + 64);
#pragma unroll
    for (int j = 0; j < 4; ++j) qA[j] = *reinterpret_cast<const float4*>(asrc_[j] + 96);
    __syncthreads();   // the ONLY barrier: Q visible to all waves

#pragma unroll
    for (int t = 0; t < 16; ++t) {
        Frag fa[2], fb[2];
#pragma unroll
        for (int ii = 0; ii < 2; ++ii) {
            fa[ii].v4[0] = *(const bf16x4_t*)(asb + ard0[ii]);
            fa[ii].v4[1] = *(const bf16x4_t*)(asb + ard1[ii]);
        }
#pragma unroll
        for (int f = 0; f < 2; ++f) {
            fb[f].v4[0] = *(const bf16x4_t*)(bsb + t * 2048 + brd0[f]);
            fb[f].v4[1] = *(const bf16x4_t*)(bsb + t * 2048 + brd1[f]);
        }
#pragma unroll
        for (int ii = 0; ii < 2; ++ii)
#pragma unroll
            for (int f = 0; f < 2; ++f)
                acc[ii][f] = __builtin_amdgcn_mfma_f32_16x16x32_bf16(fa[ii].v8, fb[f].v8, acc[ii][f], 0, 0, 0);

        if (t < 15) {
            // convert chunk t+1 (slot (t+1)%3), overwrite single buffer:
            // program-order after this iter's fa reads; same-wave in-order DS
            // + wave-private rows -> race-free without barriers.
            const int slot = (t + 1) % 3;
            if (slot == 0) {
#pragma unroll
                for (int j = 0; j < 4; ++j) {
                    ushort4_t pk;
#pragma unroll
                    for (int e = 0; e < 4; ++e) pk[e] = f2bf(qA[j][e]);
                    *(ushort4_t*)((char*)asb + awr_[j]) = pk;
                }
            } else if (slot == 1) {
#pragma unroll
                for (int j = 0; j < 4; ++j) {
                    ushort4_t pk;
#pragma unroll
                    for (int e = 0; e < 4; ++e) pk[e] = f2bf(qB[j][e]);
                    *(ushort4_t*)((char*)asb + awr_[j]) = pk;
                }
            } else {
#pragma unroll
                for (int j = 0; j < 4; ++j) {
                    ushort4_t pk;
#pragma unroll
                    for (int e = 0; e < 4; ++e) pk[e] = f2bf(qC[j][e]);
                    *(ushort4_t*)((char*)asb + awr_[j]) = pk;
                }
            }

            // refill the just-freed slot with chunk t+4 (3-iter cover)
            if (t + 4 <= 15) {
                const int off = (t + 4) * 32;
                if (slot == 0) {
#pragma unroll
                    for (int j = 0; j < 4; ++j) qA[j] = *reinterpret_cast<const float4*>(asrc_[j] + off);
                } else if (slot == 1) {
#pragma unroll
                    for (int j = 0; j < 4; ++j) qB[j] = *reinterpret_cast<const float4*>(asrc_[j] + off);
                } else {
#pragma unroll
                    for (int j = 0; j < 4; ++j) qC[j] = *reinterpret_cast<const float4*>(asrc_[j] + off);
                }
            }
        }
    }

    // epilogue: G[row][l15] = f@Q1, G[row][12+l15] = f@Q2
    const int rq_ = (lane >> 4) << 2;
#pragma unroll
    for (int ii = 0; ii < 2; ++ii)
#pragma unroll
        for (int r = 0; r < 4; ++r) {
            long grow = row0 + w * 32 + ii * 16 + rq_ + r;
            if (l15 < NCLS && grow < NROWS) {
                G[grow * GSTR + l15]      = acc[ii][0][r];
                G[grow * GSTR + 12 + l15] = acc[ii][1][r];
            }
        }
}

// ---------------- epilogue: logits = leaky(g[n1][0:10] + g[n2][12:22]), log_softmax ----------------
__global__ __launch_bounds__(256) void k_epi(
    const float* __restrict__ G,
    const int* __restrict__ n1, const int* __restrict__ n2,
    float* __restrict__ Out) {
    const long i = (long)blockIdx.x * 256 + threadIdx.x;
    if (i >= NROWS) return;
    const float* g1 = G + (long)n1[i] * GSTR;
    const float* g2 = G + (long)n2[i] * GSTR + 12;

    float4 a0 = *(const float4*)(g1);
    float4 a1 = *(const float4*)(g1 + 4);
    float2 a2 = *(const float2*)(g1 + 8);
    float4 b0 = *(const float4*)(g2);
    float4 b1 = *(const float4*)(g2 + 4);
    float2 b2 = *(const float2*)(g2 + 8);

    float x[NCLS] = {a0.x + b0.x, a0.y + b0.y, a0.z + b0.z, a0.w + b0.w,
                     a1.x + b1.x, a1.y + b1.y, a1.z + b1.z, a1.w + b1.w,
                     a2.x + b2.x, a2.y + b2.y};
    float m = -1e30f;
#pragma unroll
    for (int c = 0; c < NCLS; ++c) {
        x[c] = (x[c] >= 0.f) ? x[c] : LEAKY_ALPHA * x[c];
        m = fmaxf(m, x[c]);
    }
    float sum = 0.f;
#pragma unroll
    for (int c = 0; c < NCLS; ++c) sum += __expf(x[c] - m);
    const float lse = m + __logf(sum);
    float2* o = (float2*)(Out + i * NCLS);
#pragma unroll
    for (int j = 0; j < 5; ++j) {
        float2 v = {x[2 * j] - lse, x[2 * j + 1] - lse};
        o[j] = v;
    }
}

extern "C" void kernel_launch(void* const* d_in, const int* in_sizes, int n_in,
                              void* d_out, int out_size, void* d_ws, size_t ws_size,
                              hipStream_t stream) {
    const float* features = (const float*)d_in[0];
    const float* C  = (const float*)d_in[1];
    const float* W  = (const float*)d_in[2];
    const float* V  = (const float*)d_in[3];
    const int*   n1 = (const int*)d_in[4];
    const int*   n2 = (const int*)d_in[5];
    float* out = (float*)d_out;

    char* ws = (char*)d_ws;
    unsigned short* Qimg = (unsigned short*)ws;   // 32 KB
    float* G = (float*)(ws + 32768);              // 100000*24*4 = 9.6 MB

    hipLaunchKernelGGL(k_prep, dim3(64), dim3(256), 0, stream, C, W, V, Qimg);
    hipLaunchKernelGGL(k_gemm, dim3((NROWS + 127) / 128), dim3(256), 0, stream,
                       features, Qimg, G);
    hipLaunchKernelGGL(k_epi, dim3((NROWS + 255) / 256), dim3(256), 0, stream,
                       G, n1, n2, out);
}

// Round 16
// 56.338 us; speedup vs baseline: 2.8089x; 1.0253x over previous
//
#include <hip/hip_runtime.h>
#include <hip/hip_bf16.h>
#include <stdint.h>

#define NROWS 100000
#define INDIM 512
#define HID 128
#define NCLS 10
#define LEAKY_ALPHA 0.2f

typedef __bf16 bf16x8_t __attribute__((ext_vector_type(8)));
typedef __bf16 bf16x4_t __attribute__((ext_vector_type(4)));
typedef float f32x4_t __attribute__((ext_vector_type(4)));
typedef unsigned short ushort4_t __attribute__((ext_vector_type(4)));
typedef unsigned short ushort8_t __attribute__((ext_vector_type(8)));

union Frag {
    bf16x8_t v8;
    bf16x4_t v4[2];
    unsigned short u[8];
};

__device__ __forceinline__ unsigned short f2bf(float x) {
    union { __hip_bfloat16 b; unsigned short u; } cv;
    cv.b = __float2bfloat16(x);
    return cv.u;
}

__device__ __forceinline__ float bf2f(unsigned short u) {
    union { float f; unsigned int i; } v;
    v.i = ((unsigned int)u) << 16;
    return v.f;
}

// Byte address inside an [R x 32] bf16 tile image (rows paired into 128-B
// lines, 16-B units XOR-swizzled by pair&7). Bank-verified round 3; r12 PMC
// confirmed conflicts negligible.
__device__ __forceinline__ int img_addr(int r, int kk) {
    int p = r >> 1;
    int o = ((r & 1) << 6) | (kk << 1);
    return (p << 7) | ((((o >> 4) ^ (p & 7)) << 4) | (o & 15));
}

__device__ __forceinline__ void gload_lds16(const void* g, void* l) {
    __builtin_amdgcn_global_load_lds(
        (const __attribute__((address_space(1))) unsigned int*)g,
        (__attribute__((address_space(3))) unsigned int*)l, 16, 0, 0);
}

// ---------------- prep: Qimg = swizzled tile images of Q = [C@(W1@V) | C@(W2@V)] ----------------
// 64 blocks; block b produces k-rows [b*8, b*8+8).
__global__ __launch_bounds__(256) void k_prep(
    const float* __restrict__ C, const float* __restrict__ W, const float* __restrict__ V,
    unsigned short* __restrict__ Qimg) {
    __shared__ float Vl[HID * NCLS];
    __shared__ float Pl[2][HID][10];
    __shared__ float Cl[8][132];

    const int tid = threadIdx.x, b = blockIdx.x;
    for (int i = tid; i < HID * NCLS; i += 256) Vl[i] = V[i];
    __syncthreads();

    {
        const int half = tid >> 7, j = tid & 127;
        const float* wr = W + (half * HID + j) * HID;
        float s[NCLS];
#pragma unroll
        for (int c = 0; c < NCLS; ++c) s[c] = 0.f;
        for (int m = 0; m < HID; m += 4) {
            float4 wv = *reinterpret_cast<const float4*>(wr + m);
            float wa[4] = {wv.x, wv.y, wv.z, wv.w};
#pragma unroll
            for (int u = 0; u < 4; ++u)
#pragma unroll
                for (int c = 0; c < NCLS; ++c) s[c] += wa[u] * Vl[(m + u) * NCLS + c];
        }
#pragma unroll
        for (int c = 0; c < NCLS; ++c) Pl[half][j][c] = s[c];
    }
    const int k0 = b << 3;
    {
        const int kr = tid >> 5, ns = (tid & 31) << 2;
        *reinterpret_cast<float4*>(&Cl[kr][ns]) =
            *reinterpret_cast<const float4*>(C + (k0 + kr) * HID + ns);
    }
    __syncthreads();

    {
        const int n = tid >> 3, kl = tid & 7;
        const int half = n >> 4, c = n & 15;
        float s = 0.f;
        if (c < NCLS) {
#pragma unroll 4
            for (int j = 0; j < HID; ++j) s += Cl[kl][j] * Pl[half][j][c];
        }
        const int k = k0 + kl, t = k >> 5, kk = k & 31;
        *(unsigned short*)((char*)Qimg + t * 2048 + img_addr(n, kk)) = f2bf(s);
    }
}

// ---------------- thin GEMM: g = f @ Q  (coalesced staging + DEPTH-4 queue @ 4 blk/CU) ----------------
// BM=128, 4 waves. Lane-along-k staging (full 128-B-line wave requests),
// wave-private rows -> barrier-free single-buffer loop. Depth-4 register
// queue (chunk c in slot c%4, refill t+5): 16 outstanding sequential loads
// per thread feed the DRAM controller's page-reorder window. LDS 40 KB.
__global__ __launch_bounds__(256, 4) void k_gemm(
    const float* __restrict__ A,             // [NROWS][512] f32
    const unsigned short* __restrict__ Qimg, // 16 x 2KB swizzled tile images
    unsigned short* __restrict__ G)          // [NROWS][32] bf16 (cols 0..9 / 16..25)
{
    __shared__ unsigned short Qs[16384];     // 32 KB
    __shared__ unsigned short As[4096];      // 8 KB single buffer

    const int tid  = threadIdx.x;
    const int w    = tid >> 6;
    const int lane = tid & 63;
    const int l15  = lane & 15;
    const int kg   = (lane >> 4) << 2;
    const long row0 = (long)blockIdx.x * 128;

    // stage all of Q once (wave-uniform dests)
#pragma unroll
    for (int j = 0; j < 8; ++j) {
        const int off = (j * 4 + w) * 1024;
        gload_lds16((const char*)Qimg + off + lane * 16, (char*)Qs + off);
    }

    // A staging: pass j -> local row 32w + 8j + (lane>>3), float seg (lane&7)*4
    const int kseg = (lane & 7) << 2;
    const float* asrc_[4];
    int awr_[4];
#pragma unroll
    for (int j = 0; j < 4; ++j) {
        const int lr = w * 32 + j * 8 + (lane >> 3);
        long gr = row0 + lr;
        if (gr >= NROWS) gr = NROWS - 1;
        asrc_[j] = A + gr * INDIM + kseg;
        awr_[j] = img_addr(lr, kseg);
    }

    int ard0[2], ard1[2], brd0[2], brd1[2];
#pragma unroll
    for (int ii = 0; ii < 2; ++ii) {
        int r = w * 32 + ii * 16 + l15;
        ard0[ii] = img_addr(r, kg);
        ard1[ii] = img_addr(r, kg + 16);
    }
#pragma unroll
    for (int f = 0; f < 2; ++f) {
        brd0[f] = img_addr(f * 16 + l15, kg);
        brd1[f] = img_addr(f * 16 + l15, kg + 16);
    }

    f32x4_t acc[2][2];
#pragma unroll
    for (int i = 0; i < 2; ++i)
#pragma unroll
        for (int f = 0; f < 2; ++f)
#pragma unroll
            for (int r = 0; r < 4; ++r) acc[i][f][r] = 0.f;

    const char* asb = (const char*)&As[0];
    const char* bsb = (const char*)&Qs[0];

    float4 qA[4], qB[4], qC[4], qD[4];   // chunk c lives in slot c%4 (static names)

#define CVT_STORE(q)                                                         \
    {                                                                        \
        _Pragma("unroll")                                                    \
        for (int j = 0; j < 4; ++j) {                                        \
            ushort4_t pk;                                                    \
            _Pragma("unroll")                                                \
            for (int e = 0; e < 4; ++e) pk[e] = f2bf(q[j][e]);               \
            *(ushort4_t*)((char*)asb + awr_[j]) = pk;                        \
        }                                                                    \
    }
#define LOADQ(q, off)                                                        \
    {                                                                        \
        _Pragma("unroll")                                                    \
        for (int j = 0; j < 4; ++j)                                          \
            q[j] = *reinterpret_cast<const float4*>(asrc_[j] + (off));       \
    }

    // prologue: chunk 0 staged directly; chunks 1,2,3,4 -> slots 1,2,3,0
    {
        float4 v[4];
        LOADQ(v, 0)
        CVT_STORE(v)
    }
    LOADQ(qB, 32)
    LOADQ(qC, 64)
    LOADQ(qD, 96)
    LOADQ(qA, 128)
    __syncthreads();   // the ONLY barrier: Q visible to all waves

#pragma unroll
    for (int t = 0; t < 16; ++t) {
        Frag fa[2], fb[2];
#pragma unroll
        for (int ii = 0; ii < 2; ++ii) {
            fa[ii].v4[0] = *(const bf16x4_t*)(asb + ard0[ii]);
            fa[ii].v4[1] = *(const bf16x4_t*)(asb + ard1[ii]);
        }
#pragma unroll
        for (int f = 0; f < 2; ++f) {
            fb[f].v4[0] = *(const bf16x4_t*)(bsb + t * 2048 + brd0[f]);
            fb[f].v4[1] = *(const bf16x4_t*)(bsb + t * 2048 + brd1[f]);
        }
#pragma unroll
        for (int ii = 0; ii < 2; ++ii)
#pragma unroll
            for (int f = 0; f < 2; ++f)
                acc[ii][f] = __builtin_amdgcn_mfma_f32_16x16x32_bf16(fa[ii].v8, fb[f].v8, acc[ii][f], 0, 0, 0);

        if (t < 15) {
            // convert chunk t+1 (slot (t+1)%4), overwrite single buffer:
            // program-order after this iter's fa reads; same-wave in-order DS
            // + wave-private rows -> race-free without barriers.
            const int slot = (t + 1) & 3;
            if (slot == 0)      { CVT_STORE(qA) }
            else if (slot == 1) { CVT_STORE(qB) }
            else if (slot == 2) { CVT_STORE(qC) }
            else                { CVT_STORE(qD) }

            // refill the just-freed slot with chunk t+5 (4-iter cover)
            if (t + 5 <= 15) {
                const int off = (t + 5) * 32;
                if (slot == 0)      { LOADQ(qA, off) }
                else if (slot == 1) { LOADQ(qB, off) }
                else if (slot == 2) { LOADQ(qC, off) }
                else                { LOADQ(qD, off) }
            }
        }
    }

    // epilogue: G row = 32 bf16; cols [0,10) = f@Q1, cols [16,26) = f@Q2
    const int rq_ = (lane >> 4) << 2;
#pragma unroll
    for (int ii = 0; ii < 2; ++ii)
#pragma unroll
        for (int r = 0; r < 4; ++r) {
            long grow = row0 + w * 32 + ii * 16 + rq_ + r;
            if (l15 < NCLS && grow < NROWS) {
                G[grow * 32 + l15]      = f2bf(acc[ii][0][r]);
                G[grow * 32 + 16 + l15] = f2bf(acc[ii][1][r]);
            }
        }
}

// ---------------- epilogue: logits = leaky(g1[n1] + g2[n2]), log_softmax ----------------
__global__ __launch_bounds__(256) void k_epi(
    const unsigned short* __restrict__ G,
    const int* __restrict__ n1, const int* __restrict__ n2,
    float* __restrict__ Out) {
    const long i = (long)blockIdx.x * 256 + threadIdx.x;
    if (i >= NROWS) return;
    const ushort8_t* p1 = (const ushort8_t*)(G + (long)n1[i] * 32);
    const ushort8_t* p2 = (const ushort8_t*)(G + (long)n2[i] * 32 + 16);
    ushort8_t a0 = p1[0], a1 = p1[1];
    ushort8_t b0 = p2[0], b1 = p2[1];

    float x[NCLS];
#pragma unroll
    for (int c = 0; c < 8; ++c) x[c] = bf2f(a0[c]) + bf2f(b0[c]);
    x[8] = bf2f(a1[0]) + bf2f(b1[0]);
    x[9] = bf2f(a1[1]) + bf2f(b1[1]);

    float m = -1e30f;
#pragma unroll
    for (int c = 0; c < NCLS; ++c) {
        x[c] = (x[c] >= 0.f) ? x[c] : LEAKY_ALPHA * x[c];
        m = fmaxf(m, x[c]);
    }
    float sum = 0.f;
#pragma unroll
    for (int c = 0; c < NCLS; ++c) sum += __expf(x[c] - m);
    const float lse = m + __logf(sum);
    float2* o = (float2*)(Out + i * NCLS);
#pragma unroll
    for (int j = 0; j < 5; ++j) {
        float2 v = {x[2 * j] - lse, x[2 * j + 1] - lse};
        o[j] = v;
    }
}

extern "C" void kernel_launch(void* const* d_in, const int* in_sizes, int n_in,
                              void* d_out, int out_size, void* d_ws, size_t ws_size,
                              hipStream_t stream) {
    const float* features = (const float*)d_in[0];
    const float* C  = (const float*)d_in[1];
    const float* W  = (const float*)d_in[2];
    const float* V  = (const float*)d_in[3];
    const int*   n1 = (const int*)d_in[4];
    const int*   n2 = (const int*)d_in[5];
    float* out = (float*)d_out;

    char* ws = (char*)d_ws;
    unsigned short* Qimg = (unsigned short*)ws;          // 32 KB
    unsigned short* G = (unsigned short*)(ws + 32768);   // 100000*32*2 = 6.4 MB

    hipLaunchKernelGGL(k_prep, dim3(64), dim3(256), 0, stream, C, W, V, Qimg);
    hipLaunchKernelGGL(k_gemm, dim3((NROWS + 127) / 128), dim3(256), 0, stream,
                       features, Qimg, G);
    hipLaunchKernelGGL(k_epi, dim3((NROWS + 255) / 256), dim3(256), 0, stream,
                       G, n1, n2, out);
}

// Round 17
// 56.145 us; speedup vs baseline: 2.8185x; 1.0034x over previous
//
#include <hip/hip_runtime.h>
#include <hip/hip_bf16.h>
#include <stdint.h>

#define NROWS 100000
#define INDIM 512
#define HID 128
#define NCLS 10
#define LEAKY_ALPHA 0.2f

typedef __bf16 bf16x8_t __attribute__((ext_vector_type(8)));
typedef __bf16 bf16x4_t __attribute__((ext_vector_type(4)));
typedef float f32x4_t __attribute__((ext_vector_type(4)));
typedef unsigned short ushort4_t __attribute__((ext_vector_type(4)));
typedef unsigned short ushort8_t __attribute__((ext_vector_type(8)));

union Frag {
    bf16x8_t v8;
    bf16x4_t v4[2];
    unsigned short u[8];
};

__device__ __forceinline__ unsigned short f2bf(float x) {
    union { __hip_bfloat16 b; unsigned short u; } cv;
    cv.b = __float2bfloat16(x);
    return cv.u;
}

__device__ __forceinline__ float bf2f(unsigned short u) {
    union { float f; unsigned int i; } v;
    v.i = ((unsigned int)u) << 16;
    return v.f;
}

// Byte address inside an [R x 32] bf16 tile image (rows paired into 128-B
// lines, 16-B units XOR-swizzled by pair&7). Bank-verified round 3; r12 PMC
// confirmed conflicts negligible.
__device__ __forceinline__ int img_addr(int r, int kk) {
    int p = r >> 1;
    int o = ((r & 1) << 6) | (kk << 1);
    return (p << 7) | ((((o >> 4) ^ (p & 7)) << 4) | (o & 15));
}

__device__ __forceinline__ void gload_lds16(const void* g, void* l) {
    __builtin_amdgcn_global_load_lds(
        (const __attribute__((address_space(1))) unsigned int*)g,
        (__attribute__((address_space(3))) unsigned int*)l, 16, 0, 0);
}

// ---------------- prep: Qimg = swizzled tile images of Q = [C@(W1@V) | C@(W2@V)] ----------------
// 128 blocks; block b produces k-rows [b*4, b*4+4).
__global__ __launch_bounds__(256) void k_prep(
    const float* __restrict__ C, const float* __restrict__ W, const float* __restrict__ V,
    unsigned short* __restrict__ Qimg) {
    __shared__ float Vl[HID * NCLS];
    __shared__ float Pl[2][HID][10];
    __shared__ float Cl[4][132];

    const int tid = threadIdx.x, b = blockIdx.x;
    for (int i = tid; i < HID * NCLS; i += 256) Vl[i] = V[i];
    __syncthreads();

    // P[half][j][c] = dot(W[half*128 + j, :], V[:, c])
    {
        const int half = tid >> 7, j = tid & 127;
        const float* wr = W + (half * HID + j) * HID;
        float s[NCLS];
#pragma unroll
        for (int c = 0; c < NCLS; ++c) s[c] = 0.f;
        for (int m = 0; m < HID; m += 4) {
            float4 wv = *reinterpret_cast<const float4*>(wr + m);
            float wa[4] = {wv.x, wv.y, wv.z, wv.w};
#pragma unroll
            for (int u = 0; u < 4; ++u)
#pragma unroll
                for (int c = 0; c < NCLS; ++c) s[c] += wa[u] * Vl[(m + u) * NCLS + c];
        }
#pragma unroll
        for (int c = 0; c < NCLS; ++c) Pl[half][j][c] = s[c];
    }
    // stage C rows [k0, k0+4)
    const int k0 = b << 2;
    if (tid < 128) {
        const int kr = tid >> 5, ns = (tid & 31) << 2;
        *reinterpret_cast<float4*>(&Cl[kr][ns]) =
            *reinterpret_cast<const float4*>(C + (k0 + kr) * HID + ns);
    }
    __syncthreads();

    // Q entries: 4 k x 32 n = 128 -> half the threads
    if (tid < 128) {
        const int n = tid >> 2, kl = tid & 3;
        const int half = n >> 4, c = n & 15;
        float s = 0.f;
        if (c < NCLS) {
#pragma unroll 4
            for (int j = 0; j < HID; ++j) s += Cl[kl][j] * Pl[half][j][c];
        }
        const int k = k0 + kl, t = k >> 5, kk = k & 31;
        *(unsigned short*)((char*)Qimg + t * 2048 + img_addr(n, kk)) = f2bf(s);
    }
}

// ---------------- thin GEMM: g = f @ Q  (coalesced staging + DEPTH-5 queue @ 4 blk/CU) ----------------
// BM=128, 4 waves. Lane-along-k staging (full 128-B-line wave requests),
// wave-private rows -> barrier-free single-buffer loop. Depth-5 register
// queue (chunk c in slot c%5, refill t+6): 20 outstanding sequential loads
// per thread feed the DRAM controller's page-reorder window. LDS 40 KB.
__global__ __launch_bounds__(256, 4) void k_gemm(
    const float* __restrict__ A,             // [NROWS][512] f32
    const unsigned short* __restrict__ Qimg, // 16 x 2KB swizzled tile images
    unsigned short* __restrict__ G)          // [NROWS][32] bf16 (cols 0..9 / 16..25)
{
    __shared__ unsigned short Qs[16384];     // 32 KB
    __shared__ unsigned short As[4096];      // 8 KB single buffer

    const int tid  = threadIdx.x;
    const int w    = tid >> 6;
    const int lane = tid & 63;
    const int l15  = lane & 15;
    const int kg   = (lane >> 4) << 2;
    const long row0 = (long)blockIdx.x * 128;

    // stage all of Q once (wave-uniform dests)
#pragma unroll
    for (int j = 0; j < 8; ++j) {
        const int off = (j * 4 + w) * 1024;
        gload_lds16((const char*)Qimg + off + lane * 16, (char*)Qs + off);
    }

    // A staging: pass j -> local row 32w + 8j + (lane>>3), float seg (lane&7)*4
    const int kseg = (lane & 7) << 2;
    const float* asrc_[4];
    int awr_[4];
#pragma unroll
    for (int j = 0; j < 4; ++j) {
        const int lr = w * 32 + j * 8 + (lane >> 3);
        long gr = row0 + lr;
        if (gr >= NROWS) gr = NROWS - 1;
        asrc_[j] = A + gr * INDIM + kseg;
        awr_[j] = img_addr(lr, kseg);
    }

    int ard0[2], ard1[2], brd0[2], brd1[2];
#pragma unroll
    for (int ii = 0; ii < 2; ++ii) {
        int r = w * 32 + ii * 16 + l15;
        ard0[ii] = img_addr(r, kg);
        ard1[ii] = img_addr(r, kg + 16);
    }
#pragma unroll
    for (int f = 0; f < 2; ++f) {
        brd0[f] = img_addr(f * 16 + l15, kg);
        brd1[f] = img_addr(f * 16 + l15, kg + 16);
    }

    f32x4_t acc[2][2];
#pragma unroll
    for (int i = 0; i < 2; ++i)
#pragma unroll
        for (int f = 0; f < 2; ++f)
#pragma unroll
            for (int r = 0; r < 4; ++r) acc[i][f][r] = 0.f;

    const char* asb = (const char*)&As[0];
    const char* bsb = (const char*)&Qs[0];

    float4 qA[4], qB[4], qC[4], qD[4], qE[4];   // chunk c lives in slot c%5

#define CVT_STORE(q)                                                         \
    {                                                                        \
        _Pragma("unroll")                                                    \
        for (int j = 0; j < 4; ++j) {                                        \
            ushort4_t pk;                                                    \
            _Pragma("unroll")                                                \
            for (int e = 0; e < 4; ++e) pk[e] = f2bf(q[j][e]);               \
            *(ushort4_t*)((char*)asb + awr_[j]) = pk;                        \
        }                                                                    \
    }
#define LOADQ(q, off)                                                        \
    {                                                                        \
        _Pragma("unroll")                                                    \
        for (int j = 0; j < 4; ++j)                                          \
            q[j] = *reinterpret_cast<const float4*>(asrc_[j] + (off));       \
    }

    // prologue: chunk 0 staged directly; chunks 1..5 -> slots 1,2,3,4,0
    {
        float4 v[4];
        LOADQ(v, 0)
        CVT_STORE(v)
    }
    LOADQ(qB, 32)
    LOADQ(qC, 64)
    LOADQ(qD, 96)
    LOADQ(qE, 128)
    LOADQ(qA, 160)
    __syncthreads();   // the ONLY barrier: Q visible to all waves

#pragma unroll
    for (int t = 0; t < 16; ++t) {
        Frag fa[2], fb[2];
#pragma unroll
        for (int ii = 0; ii < 2; ++ii) {
            fa[ii].v4[0] = *(const bf16x4_t*)(asb + ard0[ii]);
            fa[ii].v4[1] = *(const bf16x4_t*)(asb + ard1[ii]);
        }
#pragma unroll
        for (int f = 0; f < 2; ++f) {
            fb[f].v4[0] = *(const bf16x4_t*)(bsb + t * 2048 + brd0[f]);
            fb[f].v4[1] = *(const bf16x4_t*)(bsb + t * 2048 + brd1[f]);
        }
#pragma unroll
        for (int ii = 0; ii < 2; ++ii)
#pragma unroll
            for (int f = 0; f < 2; ++f)
                acc[ii][f] = __builtin_amdgcn_mfma_f32_16x16x32_bf16(fa[ii].v8, fb[f].v8, acc[ii][f], 0, 0, 0);

        if (t < 15) {
            // convert chunk t+1 (slot (t+1)%5), overwrite single buffer:
            // program-order after this iter's fa reads; same-wave in-order DS
            // + wave-private rows -> race-free without barriers.
            const int slot = (t + 1) % 5;
            if (slot == 0)      { CVT_STORE(qA) }
            else if (slot == 1) { CVT_STORE(qB) }
            else if (slot == 2) { CVT_STORE(qC) }
            else if (slot == 3) { CVT_STORE(qD) }
            else                { CVT_STORE(qE) }

            // refill the just-freed slot with chunk t+6 (5-iter cover)
            if (t + 6 <= 15) {
                const int off = (t + 6) * 32;
                if (slot == 0)      { LOADQ(qA, off) }
                else if (slot == 1) { LOADQ(qB, off) }
                else if (slot == 2) { LOADQ(qC, off) }
                else if (slot == 3) { LOADQ(qD, off) }
                else                { LOADQ(qE, off) }
            }
        }
    }

    // epilogue: G row = 32 bf16; cols [0,10) = f@Q1, cols [16,26) = f@Q2
    const int rq_ = (lane >> 4) << 2;
#pragma unroll
    for (int ii = 0; ii < 2; ++ii)
#pragma unroll
        for (int r = 0; r < 4; ++r) {
            long grow = row0 + w * 32 + ii * 16 + rq_ + r;
            if (l15 < NCLS && grow < NROWS) {
                G[grow * 32 + l15]      = f2bf(acc[ii][0][r]);
                G[grow * 32 + 16 + l15] = f2bf(acc[ii][1][r]);
            }
        }
}

// ---------------- epilogue: logits = leaky(g1[n1] + g2[n2]), log_softmax ----------------
__global__ __launch_bounds__(256) void k_epi(
    const unsigned short* __restrict__ G,
    const int* __restrict__ n1, const int* __restrict__ n2,
    float* __restrict__ Out) {
    const long i = (long)blockIdx.x * 256 + threadIdx.x;
    if (i >= NROWS) return;
    const ushort8_t* p1 = (const ushort8_t*)(G + (long)n1[i] * 32);
    const ushort8_t* p2 = (const ushort8_t*)(G + (long)n2[i] * 32 + 16);
    ushort8_t a0 = p1[0], a1 = p1[1];
    ushort8_t b0 = p2[0], b1 = p2[1];

    float x[NCLS];
#pragma unroll
    for (int c = 0; c < 8; ++c) x[c] = bf2f(a0[c]) + bf2f(b0[c]);
    x[8] = bf2f(a1[0]) + bf2f(b1[0]);
    x[9] = bf2f(a1[1]) + bf2f(b1[1]);

    float m = -1e30f;
#pragma unroll
    for (int c = 0; c < NCLS; ++c) {
        x[c] = (x[c] >= 0.f) ? x[c] : LEAKY_ALPHA * x[c];
        m = fmaxf(m, x[c]);
    }
    float sum = 0.f;
#pragma unroll
    for (int c = 0; c < NCLS; ++c) sum += __expf(x[c] - m);
    const float lse = m + __logf(sum);
    float2* o = (float2*)(Out + i * NCLS);
#pragma unroll
    for (int j = 0; j < 5; ++j) {
        float2 v = {x[2 * j] - lse, x[2 * j + 1] - lse};
        o[j] = v;
    }
}

extern "C" void kernel_launch(void* const* d_in, const int* in_sizes, int n_in,
                              void* d_out, int out_size, void* d_ws, size_t ws_size,
                              hipStream_t stream) {
    const float* features = (const float*)d_in[0];
    const float* C  = (const float*)d_in[1];
    const float* W  = (const float*)d_in[2];
    const float* V  = (const float*)d_in[3];
    const int*   n1 = (const int*)d_in[4];
    const int*   n2 = (const int*)d_in[5];
    float* out = (float*)d_out;

    char* ws = (char*)d_ws;
    unsigned short* Qimg = (unsigned short*)ws;          // 32 KB
    unsigned short* G = (unsigned short*)(ws + 32768);   // 100000*32*2 = 6.4 MB

    hipLaunchKernelGGL(k_prep, dim3(128), dim3(256), 0, stream, C, W, V, Qimg);
    hipLaunchKernelGGL(k_gemm, dim3((NROWS + 127) / 128), dim3(256), 0, stream,
                       features, Qimg, G);
    hipLaunchKernelGGL(k_epi, dim3((NROWS + 255) / 256), dim3(256), 0, stream,
                       G, n1, n2, out);
}